// Round 12
// baseline (385.765 us; speedup 1.0000x reference)
//
#include <hip/hip_runtime.h>

#define N_NODES  50000
#define N_EDGES  500000
#define N_GRAPHS 2000
#define HID      145
#define HID2     72
#define N_LAYERS 4
#define EPS      1e-5f
#define HWS_LD   160   // fp16 gather row stride: 320B = 5 aligned 64B lines
#define AGG_LD   152   // fp16 agg/h row stride: 304B, 16B-aligned rows (f16x8 chunks)
#define BR       64    // rows per GEMM block
#define TSB      168   // fp16 tile stride (halves): 336B rows -> b128 frag reads 2-way (free)
#define NBKT     32    // BN-stat atomic buckets (per layer)
#define GPSZ     (NBKT * 2 * AGG_LD)   // floats per layer bucket set
#define NB_FILL  ((N_EDGES + 255) / 256)   // 1954

typedef __attribute__((ext_vector_type(4))) float f32x4;
typedef __attribute__((ext_vector_type(2))) _Float16 f16x2;
typedef __attribute__((ext_vector_type(8))) _Float16 f16x8;

#define RFL(v) __builtin_amdgcn_readfirstlane(v)

// ---------------- zero (hist + all 4 layer bucket sets) ----------------

__global__ void k_zero(int* __restrict__ hist, float* __restrict__ gpart) {
    int i = blockIdx.x * 256 + threadIdx.x;
    if (i < N_NODES) hist[i] = 0;
    if (i < N_LAYERS * GPSZ) gpart[i] = 0.f;
}

// ---------------- CSR build ----------------

__global__ void k_hist(const int* __restrict__ col, int* __restrict__ hist) {
    int i = blockIdx.x * 256 + threadIdx.x;
    if (i < N_EDGES) atomicAdd(&hist[col[i]], 1);
}

// merged scan: block b redundantly sums cnt[0 .. b*1024) for its offset
// (<=48K L2-hot adds over 1024 threads), then local inclusive scan.

__global__ void k_scan(const int* __restrict__ cnt, int* __restrict__ starts,
                       int* __restrict__ cursor, float* __restrict__ dis) {
    __shared__ int s[1024];
    __shared__ int sOff;
    int b = blockIdx.x, t = threadIdx.x;
    int i = b * 1024 + t;
    int v = (i < N_NODES) ? cnt[i] : 0;
    int pre = 0;
    for (int k = t; k < b * 1024; k += 1024) pre += cnt[k];
    s[t] = pre;
    __syncthreads();
    for (int d = 512; d > 0; d >>= 1) {
        if (t < d) s[t] += s[t + d];
        __syncthreads();
    }
    if (t == 0) sOff = s[0];
    __syncthreads();
    int off = sOff;
    __syncthreads();
    s[t] = v;
    __syncthreads();
    for (int d = 1; d < 1024; d <<= 1) {
        int x = (t >= d) ? s[t - d] : 0;
        __syncthreads();
        s[t] += x;
        __syncthreads();
    }
    if (i < N_NODES) {
        int st = off + s[t] - v;
        starts[i] = st;
        cursor[i] = st;
        dis[i] = rsqrtf((float)(v + 1));  // +1 self loop
    }
    if (i == 0) starts[N_NODES] = N_EDGES;
}

// ---------------- fill CSR + W-fragment pack (merged; blockIdx split) --------
// Frag fid = layer*50 + kc*10 + ct: 512 halves;
// lane l, elem j: B[k = kc*32+(l>>4)*8+j][c = ct*16+(l&15)], zero-padded.

__global__ void k_fill_wfrag(const int* __restrict__ rowv, const int* __restrict__ colv,
                             int* __restrict__ cursor, int* __restrict__ csr,
                             const float* __restrict__ Wc, _Float16* __restrict__ Wfrag) {
    int b = blockIdx.x;
    if (b < NB_FILL) {
        int e = b * 256 + threadIdx.x;
        if (e < N_EDGES) {
            int c = colv[e];
            int p = atomicAdd(&cursor[c], 1);
            csr[p] = rowv[e];
        }
    } else {
        int fid = (b - NB_FILL) * 4 + (threadIdx.x >> 6);   // 0..199
        int l = threadIdx.x & 63;
        int layer = fid / 50, rem = fid - layer * 50;
        int kc = rem / 10, ct = rem - kc * 10;
        const float* Wl = Wc + (size_t)layer * HID * HID;
        _Float16* base = Wfrag + (size_t)fid * 512 + l * 8;
#pragma unroll
        for (int j = 0; j < 8; j++) {
            int k = kc * 32 + (l >> 4) * 8 + j;
            int c = ct * 16 + (l & 15);
            float v = (k < HID && c < HID) ? Wl[k * HID + c] : 0.f;
            base[j] = (_Float16)v;
        }
    }
}

// ---------------- fused (BN-coef + BN-apply | embed) + MFMA GEMM ----------------
// Phase 0 (MODE 1): per-block redundant BN coefficient compute from the
//          previous layer's gpart buckets (37KB, L2-hot broadcast) -> sA/sB.
// Phase 1 (vectorized f16x8): v = relu(A*agg+B)+h_old (MODE 1) or emb[x]
//          (MODE 0); v stored fp16 to h AND the LDS tile (same f16x8 pack).
// Phase 2: 8 waves: rt = w&3 (16-row tile), col-half = (w>>2)*5 (5 x 16-col
//          tiles); K = 5 chunks of 32; 1 fp16 MFMA per (ct,kc).
// Epilogue scales by dis, converts to fp16 -> hws (pad cols are exact zeros).

#define MFMA16(a, b, c) __builtin_amdgcn_mfma_f32_16x16x32_f16(a, b, c, 0, 0, 0)

template <int MODE>
__global__ __launch_bounds__(512, 6) void k_gemm_fused(
    const _Float16* __restrict__ wfb, const float* __restrict__ dis,
    const int* __restrict__ x, const float* __restrict__ emb,
    const _Float16* __restrict__ agg, const float* __restrict__ gpart,
    const float* __restrict__ gamma, const float* __restrict__ beta,
    _Float16* __restrict__ h, _Float16* __restrict__ hws) {
    __shared__ _Float16 tile[BR * TSB];
    __shared__ float sA[HID], sB[HID];
    int t = threadIdx.x;
    int rbase = blockIdx.x * BR;
    if (MODE == 1 && t < HID) {
        float s_ = 0.f, q_ = 0.f;
        for (int b = 0; b < NBKT; b++) {
            s_ += gpart[b * (2 * AGG_LD) + t];
            q_ += gpart[b * (2 * AGG_LD) + AGG_LD + t];
        }
        const float inv = 1.f / (float)N_NODES;
        float mu = s_ * inv;
        float var = q_ * inv - mu * mu;
        float a = gamma[t] * rsqrtf(var + EPS);
        sA[t] = a;
        sB[t] = beta[t] - mu * a;
    }
    __syncthreads();
    for (int idx = t; idx < BR * 19; idx += 512) {
        int r = idx / 19;
        int c = idx - r * 19;
        int f0 = c * 8;
        int gr = rbase + r;
        f16x8 hst = {};
        if (gr < N_NODES) {
            size_t base = (size_t)gr * AGG_LD + f0;
            if (MODE == 0) {
                const float* er = emb + x[gr] * HID;
#pragma unroll
                for (int j = 0; j < 8; j++) {
                    int f = f0 + j;
                    hst[j] = (_Float16)((f < HID) ? er[f] : 0.f);
                }
            } else {
                f16x8 av = *(const f16x8*)(agg + base);
                f16x8 hv = *(const f16x8*)(h + base);
#pragma unroll
                for (int j = 0; j < 8; j++) {
                    int f = f0 + j;
                    float vj = 0.f;
                    if (f < HID) {
                        vj = fmaf(sA[f], (float)av[j], sB[f]);
                        vj = fmaxf(vj, 0.f) + (float)hv[j];
                    }
                    hst[j] = (_Float16)vj;
                }
            }
            *(f16x8*)(h + base) = hst;
        }
        *(f16x8*)&tile[r * TSB + f0] = hst;
    }
    // zero K-padding cols [152,160)
    if (t < BR) {
        f16x8 z = {};
        *(f16x8*)&tile[t * TSB + 152] = z;
    }
    __syncthreads();

    int w = t >> 6, l = t & 63;
    int rt = w & 3;
    int c5 = (w >> 2) * 5;                 // col-tile base: 0 or 5
    int arow = rt * 16 + (l & 15);
    int kgrp = (l >> 4) * 8;
    f32x4 acc0 = {}, acc1 = {}, acc2 = {}, acc3 = {}, acc4 = {};
#pragma unroll
    for (int kc = 0; kc < 5; kc++) {
        f16x8 ah = *(const f16x8*)&tile[arow * TSB + kc * 32 + kgrp];
        const _Float16* p = wfb + (size_t)(kc * 10 + c5) * 512 + l * 8;
        f16x8 bh;
#define STEP(ACC, CI)                                                      \
        bh = *(const f16x8*)(p + (CI) * 512);                              \
        ACC = MFMA16(ah, bh, ACC);
        STEP(acc0, 0) STEP(acc1, 1) STEP(acc2, 2) STEP(acc3, 3) STEP(acc4, 4)
#undef STEP
    }
    int rb4 = rbase + rt * 16 + (l >> 4) * 4;
    f32x4 d4 = *(const f32x4*)(dis + rb4);  // dis alloc padded; OOB lanes guarded below
    int colb = c5 * 16 + (l & 15);
#pragma unroll
    for (int r_ = 0; r_ < 4; r_++) {
        int gr = rb4 + r_;
        if (gr < N_NODES) {
            float dd = d4[r_];
            _Float16* row = hws + (size_t)gr * HWS_LD + colb;
            row[0]  = (_Float16)(acc0[r_] * dd);
            row[16] = (_Float16)(acc1[r_] * dd);
            row[32] = (_Float16)(acc2[r_] * dd);
            row[48] = (_Float16)(acc3[r_] * dd);
            row[64] = (_Float16)(acc4[r_] * dd);
        }
    }
}

// ---------------- aggregate + fused BN partial stats ----------------
// agg[i] = dis[i] * (sum_{src in N(i)} hws[src] + hws[i]); one wave per node
// (grid exact: 12500 blocks x 4 waves = 50000). Unmasked 8-wide main loop
// (plain adds) + ONE masked tail iteration. Wave-uniform scalars via
// readfirstlane (s_load csr, saddr-form gathers).
// BN stats: per-block LDS reduce (direct-indexed) -> 32-bucket global atomics.

__global__ __launch_bounds__(256) void k_agg(const _Float16* __restrict__ hws,
                                             const int* __restrict__ starts,
                                             const int* __restrict__ csr,
                                             const float* __restrict__ dis,
                                             _Float16* __restrict__ agg,
                                             float* __restrict__ gpart) {
    __shared__ float sS[4][AGG_LD], sQ[4][AGG_LD];
    int t = threadIdx.x;
    int wave = t >> 6;
    int lane = t & 63;
    int i = RFL(blockIdx.x * 4 + wave);   // always < N_NODES (exact grid)
    int s = RFL(starts[i]);
    int e = RFL(starts[i + 1]);
    bool tl = lane < 9;
    const f16x2* self = (const f16x2*)(hws + (size_t)i * HWS_LD);
    f16x2 sv = self[lane];
    float ax = (float)sv.x, ay = (float)sv.y;
    float bx = 0.f, by = 0.f;
    if (tl) { f16x2 tv = self[64 + lane]; bx = (float)tv.x; by = (float)tv.y; }

    int nfull = (e - s) & ~7;
    int efull = s + nfull;
    int j = s;
    for (; j < efull; j += 8) {
        int rb[8];
#pragma unroll
        for (int u = 0; u < 8; u++) rb[u] = RFL(csr[j + u]) * HWS_LD;
#pragma unroll
        for (int u = 0; u < 8; u++) {
            f16x2 v = ((const f16x2*)(hws + rb[u]))[lane];
            ax += (float)v.x;
            ay += (float)v.y;
        }
        if (tl) {
#pragma unroll
            for (int u = 0; u < 8; u++) {
                f16x2 v = ((const f16x2*)(hws + rb[u]))[64 + lane];
                bx += (float)v.x;
                by += (float)v.y;
            }
        }
    }
    if (j < e) {  // masked tail, single iteration (1..7 edges)
        int last = e - 1;
        int rb[8]; float m[8];
#pragma unroll
        for (int u = 0; u < 8; u++) {
            bool ok = j + u < e;
            rb[u] = RFL(csr[ok ? j + u : last]) * HWS_LD;
            m[u] = ok ? 1.f : 0.f;
        }
#pragma unroll
        for (int u = 0; u < 8; u++) {
            f16x2 v = ((const f16x2*)(hws + rb[u]))[lane];
            ax = fmaf((float)v.x, m[u], ax);
            ay = fmaf((float)v.y, m[u], ay);
        }
        if (tl) {
#pragma unroll
            for (int u = 0; u < 8; u++) {
                f16x2 v = ((const f16x2*)(hws + rb[u]))[64 + lane];
                bx = fmaf((float)v.x, m[u], bx);
                by = fmaf((float)v.y, m[u], by);
            }
        }
    }

    float di = dis[i];
    float v0 = ax * di, v1 = ay * di;          // features 2l, 2l+1
    float v2 = bx * di;                        // feature 128+2l (lane<9)
    float v3 = (lane < 8) ? by * di : 0.f;     // feature 129+2l; lane8 slot 145 = exact 0

    f16x2* o2 = (f16x2*)(agg + (size_t)i * AGG_LD);
    o2[lane] = f16x2{(_Float16)v0, (_Float16)v1};
    if (tl) o2[64 + lane] = f16x2{(_Float16)v2, (_Float16)v3};

    // per-block BN partials (direct-indexed LDS; slots 0..145 written once;
    // 146..151 unwritten -> garbage flows to skipped gpart slots only)
    sS[wave][2 * lane] = v0;     sQ[wave][2 * lane] = v0 * v0;
    sS[wave][2 * lane + 1] = v1; sQ[wave][2 * lane + 1] = v1 * v1;
    if (tl) {
        sS[wave][128 + 2 * lane] = v2; sQ[wave][128 + 2 * lane] = v2 * v2;
        sS[wave][129 + 2 * lane] = v3; sQ[wave][129 + 2 * lane] = v3 * v3;
    }
    __syncthreads();
    int bucket = blockIdx.x & (NBKT - 1);
    float* gp = gpart + (size_t)bucket * (2 * AGG_LD);
    for (int idx2 = t; idx2 < 2 * AGG_LD; idx2 += 256) {
        int f = (idx2 < AGG_LD) ? idx2 : idx2 - AGG_LD;
        if (f > HID) continue;  // skip garbage pad slots
        float v = (idx2 < AGG_LD)
                      ? ((sS[0][f] + sS[1][f]) + (sS[2][f] + sS[3][f]))
                      : ((sQ[0][f] + sQ[1][f]) + (sQ[2][f] + sQ[3][f]));
        atomicAdd(&gp[idx2], v);
    }
}

// ---------------- pool + MLP (fused layer-3 BN coef + apply), block/graph ----

__global__ __launch_bounds__(192) void k_pool_mlp(
    const _Float16* __restrict__ agg, const _Float16* __restrict__ h,
    const float* __restrict__ gpart, const float* __restrict__ gamma,
    const float* __restrict__ beta, const int* __restrict__ batch,
    const float* __restrict__ W1, const float* __restrict__ b1,
    const float* __restrict__ W2, const float* __restrict__ b2,
    float* __restrict__ out) {
    __shared__ float sA[HID], sB[HID];
    __shared__ float sH[HID];
    __shared__ float red[128];
    int f = threadIdx.x;
    if (f < HID) {
        float s_ = 0.f, q_ = 0.f;
        for (int b = 0; b < NBKT; b++) {
            s_ += gpart[b * (2 * AGG_LD) + f];
            q_ += gpart[b * (2 * AGG_LD) + AGG_LD + f];
        }
        const float inv = 1.f / (float)N_NODES;
        float mu = s_ * inv;
        float var = q_ * inv - mu * mu;
        float a = gamma[f] * rsqrtf(var + EPS);
        sA[f] = a;
        sB[f] = beta[f] - mu * a;
    }
    __syncthreads();
    int g = blockIdx.x;
    int lo = 0, hi = N_NODES;
    while (lo < hi) { int m = (lo + hi) >> 1; if (batch[m] < g) lo = m + 1; else hi = m; }
    int s = lo;
    hi = N_NODES;
    while (lo < hi) { int m = (lo + hi) >> 1; if (batch[m] < g + 1) lo = m + 1; else hi = m; }
    int e = lo;
    if (f < HID) {
        float A = sA[f], B = sB[f];
        float acc = 0.f;
        for (int n = s; n < e; n++) {
            size_t idx = (size_t)n * AGG_LD + f;
            float v = fmaf(A, (float)agg[idx], B);
            acc += fmaxf(v, 0.f) + (float)h[idx];
        }
        sH[f] = acc / fmaxf((float)(e - s), 1.f);
    }
    __syncthreads();
    int t = threadIdx.x;
    float v = 0.f;
    if (t < HID2) {
        float acc = b1[t];
        for (int k = 0; k < HID; k++) acc = fmaf(sH[k], W1[k * HID2 + t], acc);
        v = fmaxf(acc, 0.f) * W2[t];
    }
    if (t < 128) red[t] = v;
    __syncthreads();
    for (int d = 64; d > 0; d >>= 1) {
        if (t < d) red[t] += red[t + d];
        __syncthreads();
    }
    if (t == 0) out[g] = red[0] + b2[0];
}

// ---------------- host launch ----------------

extern "C" void kernel_launch(void* const* d_in, const int* in_sizes, int n_in,
                              void* d_out, int out_size, void* d_ws, size_t ws_size,
                              hipStream_t stream) {
    const int*   x     = (const int*)d_in[0];
    const int*   erow  = (const int*)d_in[1];
    const int*   ecol  = erow + N_EDGES;
    const int*   batch = (const int*)d_in[2];
    const float* emb   = (const float*)d_in[3];
    const float* Wc    = (const float*)d_in[4];
    // d_in[5] = bc: unused — BatchNorm cancels a per-feature constant shift
    const float* gamma = (const float*)d_in[6];
    const float* beta  = (const float*)d_in[7];
    const float* W1    = (const float*)d_in[8];
    const float* b1    = (const float*)d_in[9];
    const float* W2    = (const float*)d_in[10];
    const float* b2    = (const float*)d_in[11];
    float* out = (float*)d_out;

    char* wsb = (char*)d_ws;
    size_t off = 0;
    auto alloc = [&](size_t bytes) -> char* {
        char* p = wsb + off;
        off = (off + bytes + 255) & ~(size_t)255;
        return p;
    };
    int*      hist    = (int*)alloc(N_NODES * 4);
    int*      starts  = (int*)alloc((N_NODES + 1) * 4);
    int*      cursor  = (int*)alloc(N_NODES * 4);
    int*      csr     = (int*)alloc(N_EDGES * 4);
    float*    dis     = (float*)alloc((N_NODES + 64) * 4);  // padded: epilogue float4 reads
    _Float16* h       = (_Float16*)alloc((size_t)N_NODES * AGG_LD * 2);
    _Float16* hws     = (_Float16*)alloc((size_t)N_NODES * HWS_LD * 2);
    _Float16* agg     = (_Float16*)alloc((size_t)N_NODES * AGG_LD * 2);
    float*    gpart   = (float*)alloc((size_t)N_LAYERS * GPSZ * 4);  // per-layer buckets
    _Float16* Wfrag   = (_Float16*)alloc((size_t)N_LAYERS * 50 * 512 * 2);

    const int NB_SCAN = (N_NODES + 1023) / 1024;  // 49
    const int NB_GEMM = (N_NODES + BR - 1) / BR;  // 782

    // CSR build (reused across all layers) + W fragment planes + stat buckets
    k_zero<<<(N_NODES + 255) / 256, 256, 0, stream>>>(hist, gpart);
    k_hist<<<(N_EDGES + 255) / 256, 256, 0, stream>>>(ecol, hist);
    k_scan<<<NB_SCAN, 1024, 0, stream>>>(hist, starts, cursor, dis);
    k_fill_wfrag<<<NB_FILL + 50, 256, 0, stream>>>(erow, ecol, cursor, csr, Wc, Wfrag);

    for (int l = 0; l < N_LAYERS; l++) {
        const _Float16* wfb = Wfrag + (size_t)l * 50 * 512;
        if (l == 0)
            k_gemm_fused<0><<<NB_GEMM, 512, 0, stream>>>(
                wfb, dis, x, emb, agg, nullptr, nullptr, nullptr, h, hws);
        else
            k_gemm_fused<1><<<NB_GEMM, 512, 0, stream>>>(
                wfb, dis, x, emb, agg, gpart + (size_t)(l - 1) * GPSZ,
                gamma + (l - 1) * HID, beta + (l - 1) * HID, h, hws);
        k_agg<<<N_NODES / 4, 256, 0, stream>>>(hws, starts, csr, dis, agg,
                                               gpart + (size_t)l * GPSZ);
    }

    k_pool_mlp<<<N_GRAPHS, 192, 0, stream>>>(agg, h, gpart + (size_t)3 * GPSZ,
                                             gamma + 3 * HID, beta + 3 * HID,
                                             batch, W1, b1, W2, b2, out);
}